// Round 3
// baseline (57.873 us; speedup 1.0000x reference)
//
#include <hip/hip_runtime.h>

// MetaLSTM: per-param independent 16-step recurrence, memory-bound (320 MB x_all).
//   f_next = x·WF[0:20] + c*WF[20] + f*WF[21] + bF
//   i_next = x·WI[0:20] + c*WI[20] + i*WI[21] + bI
//   c_next = sigmoid(f_next)*c - sigmoid(i_next)*g[t]
// Outputs flat: [c (P), f (P), i (P)]
//
// R2: global_load_lds DMA staging (no VGPR round-trip, no ds_write), LDS
// double-buffer -> ONE barrier per step. Rotated slab layout (orig slot s of
// row r at slot (s+r)%5) achieved by pre-swizzling per-lane GLOBAL source
// addresses (DMA dest must be linear: base + lane*16). Read side <=2-way
// bank aliasing (free). 40 KB LDS -> 4 blocks/CU, 16 waves/CU.

#define BLOCK 256
#define N_IN 20
#define ROW_F4 5
#define SLAB_F4 (BLOCK * ROW_F4)  // 1280 float4 = 20 KB per buffer

#define AS_GLOBAL(p) ((const __attribute__((address_space(1))) void*)(const void*)(p))
#define AS_LDS(p)    ((__attribute__((address_space(3))) void*)(void*)(p))

__global__ __launch_bounds__(BLOCK) void metalstm_kernel(
    const float* __restrict__ x_all,  // [T, P, N]
    const float* __restrict__ grad,   // [T]
    const float* __restrict__ WF,     // [22]
    const float* __restrict__ WI,     // [22]
    const float* __restrict__ cI,     // [P]
    const float* __restrict__ bF,     // [1]
    const float* __restrict__ bI,     // [1]
    float* __restrict__ out,          // [3*P]
    int P, int T)
{
    __shared__ __align__(16) float4 xs4[2][SLAB_F4];  // 40 KB

    const int tid = threadIdx.x;
    const int w = tid >> 6;      // wave id in block
    const int l = tid & 63;      // lane id
    const int pbase = blockIdx.x * BLOCK;
    const int p = pbase + tid;
    const bool valid = (p < P);
    const int pc = valid ? p : (P - 1);

    // Wave-uniform weights/biases.
    float wF[22], wI[22];
#pragma unroll
    for (int k = 0; k < 22; ++k) { wF[k] = WF[k]; wI[k] = WI[k]; }
    const float biasF = bF[0];
    const float biasI = bI[0];

    // ---- Per-lane pre-swizzled global source pointers (5 DMA issues). ----
    // DMA issue k of wave w fills LDS f4 positions q = k*BLOCK + w*64 + l.
    // Position q must hold global (row=q/5 clamped, slot=(q%5 - row) mod 5)
    // so that the read-side rotation (slot jj at (jj+row)%5) round-trips.
    const char* __restrict__ xbytes = (const char*)x_all;
    const long stepBytes = (long)P * (N_IN * 4);  // 80 B per row
#define MKSRC(k, ptrvar) const char* ptrvar; { \
        const int q = (k) * BLOCK + w * 64 + l; \
        const int row = q / ROW_F4; \
        int slot = (q - row * ROW_F4) - (row % ROW_F4); \
        if (slot < 0) slot += ROW_F4; \
        int srcrow = pbase + row; if (srcrow >= P) srcrow = P - 1; \
        ptrvar = xbytes + ((long)srcrow * ROW_F4 + slot) * 16; }
    MKSRC(0, src0) MKSRC(1, src1) MKSRC(2, src2) MKSRC(3, src3) MKSRC(4, src4)
#undef MKSRC

    // LDS destinations are wave-uniform (linear chunks), one per issue.
#define ISSUE(bufidx) { \
        __builtin_amdgcn_global_load_lds(AS_GLOBAL(src0), AS_LDS(&xs4[bufidx][0 * BLOCK + w * 64]), 16, 0, 0); \
        __builtin_amdgcn_global_load_lds(AS_GLOBAL(src1), AS_LDS(&xs4[bufidx][1 * BLOCK + w * 64]), 16, 0, 0); \
        __builtin_amdgcn_global_load_lds(AS_GLOBAL(src2), AS_LDS(&xs4[bufidx][2 * BLOCK + w * 64]), 16, 0, 0); \
        __builtin_amdgcn_global_load_lds(AS_GLOBAL(src3), AS_LDS(&xs4[bufidx][3 * BLOCK + w * 64]), 16, 0, 0); \
        __builtin_amdgcn_global_load_lds(AS_GLOBAL(src4), AS_LDS(&xs4[bufidx][4 * BLOCK + w * 64]), 16, 0, 0); \
        src0 += stepBytes; src1 += stepBytes; src2 += stepBytes; \
        src3 += stepBytes; src4 += stepBytes; }

    float f = 0.0f;
    float ii = 0.0f;
    float c = cI[pc];

    // Prologue: DMA step-0 slab into buffer 0.
    ISSUE(0)
    __syncthreads();  // implicit vmcnt(0) drain -> slab 0 resident

    const int rbase = tid * ROW_F4;
    const int rrot = tid % ROW_F4;

    for (int t = 0; t < T; ++t) {
        const int cur = t & 1;
        // Issue next step's DMA into the other buffer (reads of it finished
        // at the barrier that ended iteration t-1).
        if (t + 1 < T) { ISSUE(cur ^ 1) }

        const float g_t = grad[t];

        // Read own row from rotated slab: slot (jj+tid)%5 holds orig slot jj.
        float dF = biasF, dI = biasI;
#define ACC4(jj) { int slr = (jj) + rrot; if (slr >= ROW_F4) slr -= ROW_F4; \
                   const float4 v = xs4[cur][rbase + slr]; \
                   dF = fmaf(v.x, wF[4*(jj)+0], dF); dI = fmaf(v.x, wI[4*(jj)+0], dI); \
                   dF = fmaf(v.y, wF[4*(jj)+1], dF); dI = fmaf(v.y, wI[4*(jj)+1], dI); \
                   dF = fmaf(v.z, wF[4*(jj)+2], dF); dI = fmaf(v.z, wI[4*(jj)+2], dI); \
                   dF = fmaf(v.w, wF[4*(jj)+3], dF); dI = fmaf(v.w, wI[4*(jj)+3], dI); }
        ACC4(0) ACC4(1) ACC4(2) ACC4(3) ACC4(4)
#undef ACC4

        const float fn  = fmaf(c, wF[20], fmaf(f,  wF[21], dF));
        const float in_ = fmaf(c, wI[20], fmaf(ii, wI[21], dI));
        const float sf = 1.0f / (1.0f + __expf(-fn));
        const float si = 1.0f / (1.0f + __expf(-in_));
        c = sf * c - si * g_t;
        f = fn;
        ii = in_;

        // One barrier per step: drains this wave's DMA for t+1 (vmcnt(0))
        // and ensures all waves finished reading xs4[cur].
        __syncthreads();
    }
#undef ISSUE

    if (valid) {
        out[p]         = c;
        out[P + p]     = f;
        out[2 * P + p] = ii;
    }
}

extern "C" void kernel_launch(void* const* d_in, const int* in_sizes, int n_in,
                              void* d_out, int out_size, void* d_ws, size_t ws_size,
                              hipStream_t stream) {
    const float* x_all = (const float*)d_in[0];
    const float* grad  = (const float*)d_in[1];
    const float* WF    = (const float*)d_in[2];
    const float* WI    = (const float*)d_in[3];
    const float* cI    = (const float*)d_in[4];
    const float* bF    = (const float*)d_in[5];
    const float* bI    = (const float*)d_in[6];
    float* out = (float*)d_out;

    const int P = in_sizes[4];
    const int T = in_sizes[1];
    const int grid = (P + BLOCK - 1) / BLOCK;
    metalstm_kernel<<<grid, BLOCK, 0, stream>>>(x_all, grad, WF, WI, cI, bF, bI, out, P, T);
}

// Round 4
// 56.016 us; speedup vs baseline: 1.0331x; 1.0331x over previous
//
#include <hip/hip_runtime.h>

// MetaLSTM: per-param independent 16-step recurrence, memory-bound (320 MB x_all).
//   f_next = x·WF[0:20] + c*WF[20] + f*WF[21] + bF
//   i_next = x·WI[0:20] + c*WI[20] + i*WI[21] + bI
//   c_next = sigmoid(f_next)*c - sigmoid(i_next)*g[t]
// Outputs flat: [c (P), f (P), i (P)]
//
// R4: wave-private LDS staging, ZERO s_barriers. Each wave stages its own
// 64 rows (5 KB region) with coalesced float4 loads; cross-lane visibility
// within a wave needs only s_waitcnt lgkmcnt(0) (lockstep wave, in-order DS).
// 20 KB LDS/block -> 8 blocks/CU; waves free-run (no block convoying, no
// barrier vmcnt(0) drains). Linear layout: write side conflict-free, read
// side 2-way (free, m136). Next-step slab prefetched to regs before reads.

#define BLOCK 256
#define NWAVE (BLOCK / 64)
#define N_IN 20
#define ROW_F4 5
#define WSLAB (64 * ROW_F4)  // 320 float4 = 5 KB per wave

__global__ __launch_bounds__(BLOCK) void metalstm_kernel(
    const float* __restrict__ x_all,  // [T, P, N]
    const float* __restrict__ grad,   // [T]
    const float* __restrict__ WF,     // [22]
    const float* __restrict__ WI,     // [22]
    const float* __restrict__ cI,     // [P]
    const float* __restrict__ bF,     // [1]
    const float* __restrict__ bI,     // [1]
    float* __restrict__ out,          // [3*P]
    int P, int T)
{
    __shared__ __align__(16) float4 xs4[NWAVE][WSLAB];  // 20 KB

    const int tid = threadIdx.x;
    const int w = tid >> 6;
    const int l = tid & 63;
    const int p = blockIdx.x * BLOCK + tid;
    const bool valid = (p < P);
    const int pc = valid ? p : (P - 1);

    // Wave-uniform weights/biases (uniform addresses -> s_loads/SGPRs).
    float wF[22], wI[22];
#pragma unroll
    for (int k = 0; k < 22; ++k) { wF[k] = WF[k]; wI[k] = WI[k]; }
    const float biasF = bF[0];
    const float biasI = bI[0];

    const int wrow0 = blockIdx.x * BLOCK + (w << 6);  // wave's first param row
    const float4* __restrict__ x4 = reinterpret_cast<const float4*>(x_all);

    // f4-index bookkeeping (max index 16*250000*5 = 20M, fits u32).
    const unsigned stepF4 = (unsigned)P * ROW_F4;
    unsigned base4 = (unsigned)wrow0 * ROW_F4;  // step-0 base for this wave
    unsigned end4  = stepF4;                    // step-0 exclusive end (clamp for tail)

    // Coalesced prefetch: lane l, issue k -> wave-region f4 q = k*64+l.
    float4 pr0, pr1, pr2, pr3, pr4;
#define PREF() { \
    unsigned i0 = base4 + 0 * 64 + l; if (i0 >= end4) i0 = end4 - 1; \
    unsigned i1 = base4 + 1 * 64 + l; if (i1 >= end4) i1 = end4 - 1; \
    unsigned i2 = base4 + 2 * 64 + l; if (i2 >= end4) i2 = end4 - 1; \
    unsigned i3 = base4 + 3 * 64 + l; if (i3 >= end4) i3 = end4 - 1; \
    unsigned i4 = base4 + 4 * 64 + l; if (i4 >= end4) i4 = end4 - 1; \
    pr0 = x4[i0]; pr1 = x4[i1]; pr2 = x4[i2]; pr3 = x4[i3]; pr4 = x4[i4]; }

    PREF()  // step 0 slab -> regs

    float f = 0.0f;
    float ii = 0.0f;
    float c = cI[pc];

    for (int t = 0; t < T; ++t) {
        // Pin order: reads of step t-1 (prev iter) stay before these writes.
        __builtin_amdgcn_sched_barrier(0);

        // Write prefetched slab into own wave region (linear, conflict-free;
        // compiler inserts vmcnt waits for the pr* global loads here).
        xs4[w][0 * 64 + l] = pr0;
        xs4[w][1 * 64 + l] = pr1;
        xs4[w][2 * 64 + l] = pr2;
        xs4[w][3 * 64 + l] = pr3;
        xs4[w][4 * 64 + l] = pr4;
        // Wave-local visibility: all 64 lanes' ds_writes complete.
        asm volatile("s_waitcnt lgkmcnt(0)" ::: "memory");
        __builtin_amdgcn_sched_barrier(0);

        // Prefetch next step's slab (in flight during compute below).
        if (t + 1 < T) { base4 += stepF4; end4 += stepF4; PREF() }

        const float g_t = grad[t];

        // Read own row: slots 5l..5l+4 (2-way bank aliasing = free).
        float dF = biasF, dI = biasI;
        const int rb = l * ROW_F4;
#pragma unroll
        for (int jj = 0; jj < ROW_F4; ++jj) {
            const float4 v = xs4[w][rb + jj];
            dF = fmaf(v.x, wF[4 * jj + 0], dF); dI = fmaf(v.x, wI[4 * jj + 0], dI);
            dF = fmaf(v.y, wF[4 * jj + 1], dF); dI = fmaf(v.y, wI[4 * jj + 1], dI);
            dF = fmaf(v.z, wF[4 * jj + 2], dF); dI = fmaf(v.z, wI[4 * jj + 2], dI);
            dF = fmaf(v.w, wF[4 * jj + 3], dF); dI = fmaf(v.w, wI[4 * jj + 3], dI);
        }
#undef PREF

        const float fn  = fmaf(c, wF[20], fmaf(f,  wF[21], dF));
        const float in_ = fmaf(c, wI[20], fmaf(ii, wI[21], dI));
        const float sf = 1.0f / (1.0f + __expf(-fn));
        const float si = 1.0f / (1.0f + __expf(-in_));
        c = sf * c - si * g_t;
        f = fn;
        ii = in_;
    }

    if (valid) {
        out[p]         = c;
        out[P + p]     = f;
        out[2 * P + p] = ii;
    }
}

extern "C" void kernel_launch(void* const* d_in, const int* in_sizes, int n_in,
                              void* d_out, int out_size, void* d_ws, size_t ws_size,
                              hipStream_t stream) {
    const float* x_all = (const float*)d_in[0];
    const float* grad  = (const float*)d_in[1];
    const float* WF    = (const float*)d_in[2];
    const float* WI    = (const float*)d_in[3];
    const float* cI    = (const float*)d_in[4];
    const float* bF    = (const float*)d_in[5];
    const float* bI    = (const float*)d_in[6];
    float* out = (float*)d_out;

    const int P = in_sizes[4];
    const int T = in_sizes[1];
    const int grid = (P + BLOCK - 1) / BLOCK;
    metalstm_kernel<<<grid, BLOCK, 0, stream>>>(x_all, grad, WF, WI, cI, bF, bI, out, P, T);
}

// Round 6
// 53.805 us; speedup vs baseline: 1.0756x; 1.0411x over previous
//
#include <hip/hip_runtime.h>

// MetaLSTM: per-param independent 16-step recurrence, memory-bound (320 MB x_all).
//   f_next = x·WF[0:20] + c*WF[20] + f*WF[21] + bF
//   i_next = x·WI[0:20] + c*WI[20] + i*WI[21] + bI
//   c_next = sigmoid(f_next)*c - sigmoid(i_next)*g[t]
// Outputs flat: [c (P), f (P), i (P)]
//
// R5 = R4 (wave-private LDS staging, zero s_barriers) + non-temporal
// loads/stores (via clang ext_vector float4 — HIP_vector_type isn't accepted
// by __builtin_nontemporal_load): zero-reuse stream skips cache-fill churn.

#define BLOCK 256
#define NWAVE (BLOCK / 64)
#define N_IN 20
#define ROW_F4 5
#define WSLAB (64 * ROW_F4)  // 320 float4 = 5 KB per wave

typedef float nf4 __attribute__((ext_vector_type(4)));

__global__ __launch_bounds__(BLOCK) void metalstm_kernel(
    const float* __restrict__ x_all,  // [T, P, N]
    const float* __restrict__ grad,   // [T]
    const float* __restrict__ WF,     // [22]
    const float* __restrict__ WI,     // [22]
    const float* __restrict__ cI,     // [P]
    const float* __restrict__ bF,     // [1]
    const float* __restrict__ bI,     // [1]
    float* __restrict__ out,          // [3*P]
    int P, int T)
{
    __shared__ __align__(16) nf4 xs4[NWAVE][WSLAB];  // 20 KB

    const int tid = threadIdx.x;
    const int w = tid >> 6;
    const int l = tid & 63;
    const int p = blockIdx.x * BLOCK + tid;
    const bool valid = (p < P);
    const int pc = valid ? p : (P - 1);

    // Wave-uniform weights/biases.
    float wF[22], wI[22];
#pragma unroll
    for (int k = 0; k < 22; ++k) { wF[k] = WF[k]; wI[k] = WI[k]; }
    const float biasF = bF[0];
    const float biasI = bI[0];

    const int wrow0 = blockIdx.x * BLOCK + (w << 6);  // wave's first param row
    const nf4* __restrict__ x4 = reinterpret_cast<const nf4*>(x_all);

    // f4-index bookkeeping (max index 16*250000*5 = 20M, fits u32).
    const unsigned stepF4 = (unsigned)P * ROW_F4;
    unsigned base4 = (unsigned)wrow0 * ROW_F4;  // step-0 base for this wave
    unsigned end4  = stepF4;                    // step-0 exclusive end (tail clamp)

    // Coalesced non-temporal prefetch: lane l, issue k -> wave f4 q = k*64+l.
    nf4 pr0, pr1, pr2, pr3, pr4;
#define PREF() { \
    unsigned i0 = base4 + 0 * 64 + l; if (i0 >= end4) i0 = end4 - 1; \
    unsigned i1 = base4 + 1 * 64 + l; if (i1 >= end4) i1 = end4 - 1; \
    unsigned i2 = base4 + 2 * 64 + l; if (i2 >= end4) i2 = end4 - 1; \
    unsigned i3 = base4 + 3 * 64 + l; if (i3 >= end4) i3 = end4 - 1; \
    unsigned i4 = base4 + 4 * 64 + l; if (i4 >= end4) i4 = end4 - 1; \
    pr0 = __builtin_nontemporal_load(&x4[i0]); \
    pr1 = __builtin_nontemporal_load(&x4[i1]); \
    pr2 = __builtin_nontemporal_load(&x4[i2]); \
    pr3 = __builtin_nontemporal_load(&x4[i3]); \
    pr4 = __builtin_nontemporal_load(&x4[i4]); }

    PREF()  // step 0 slab -> regs

    float f = 0.0f;
    float ii = 0.0f;
    float c = cI[pc];

    for (int t = 0; t < T; ++t) {
        // Pin order: reads of step t-1 (prev iter) stay before these writes.
        __builtin_amdgcn_sched_barrier(0);

        // Write prefetched slab into own wave region (linear, conflict-free).
        xs4[w][0 * 64 + l] = pr0;
        xs4[w][1 * 64 + l] = pr1;
        xs4[w][2 * 64 + l] = pr2;
        xs4[w][3 * 64 + l] = pr3;
        xs4[w][4 * 64 + l] = pr4;
        // Wave-local visibility: all 64 lanes' ds_writes complete.
        asm volatile("s_waitcnt lgkmcnt(0)" ::: "memory");
        __builtin_amdgcn_sched_barrier(0);

        // Prefetch next step's slab (in flight during compute below).
        if (t + 1 < T) { base4 += stepF4; end4 += stepF4; PREF() }

        const float g_t = grad[t];

        // Read own row: slots 5l..5l+4 (2-way bank aliasing = free).
        float dF = biasF, dI = biasI;
        const int rb = l * ROW_F4;
#pragma unroll
        for (int jj = 0; jj < ROW_F4; ++jj) {
            const nf4 v = xs4[w][rb + jj];
            dF = fmaf(v.x, wF[4 * jj + 0], dF); dI = fmaf(v.x, wI[4 * jj + 0], dI);
            dF = fmaf(v.y, wF[4 * jj + 1], dF); dI = fmaf(v.y, wI[4 * jj + 1], dI);
            dF = fmaf(v.z, wF[4 * jj + 2], dF); dI = fmaf(v.z, wI[4 * jj + 2], dI);
            dF = fmaf(v.w, wF[4 * jj + 3], dF); dI = fmaf(v.w, wI[4 * jj + 3], dI);
        }
#undef PREF

        const float fn  = fmaf(c, wF[20], fmaf(f,  wF[21], dF));
        const float in_ = fmaf(c, wI[20], fmaf(ii, wI[21], dI));
        const float sf = 1.0f / (1.0f + __expf(-fn));
        const float si = 1.0f / (1.0f + __expf(-in_));
        c = sf * c - si * g_t;
        f = fn;
        ii = in_;
    }

    if (valid) {
        __builtin_nontemporal_store(c,  &out[p]);
        __builtin_nontemporal_store(f,  &out[P + p]);
        __builtin_nontemporal_store(ii, &out[2 * P + p]);
    }
}

extern "C" void kernel_launch(void* const* d_in, const int* in_sizes, int n_in,
                              void* d_out, int out_size, void* d_ws, size_t ws_size,
                              hipStream_t stream) {
    const float* x_all = (const float*)d_in[0];
    const float* grad  = (const float*)d_in[1];
    const float* WF    = (const float*)d_in[2];
    const float* WI    = (const float*)d_in[3];
    const float* cI    = (const float*)d_in[4];
    const float* bF    = (const float*)d_in[5];
    const float* bI    = (const float*)d_in[6];
    float* out = (float*)d_out;

    const int P = in_sizes[4];
    const int T = in_sizes[1];
    const int grid = (P + BLOCK - 1) / BLOCK;
    metalstm_kernel<<<grid, BLOCK, 0, stream>>>(x_all, grad, WF, WI, cI, bF, bI, out, P, T);
}